// Round 4
// baseline (591.863 us; speedup 1.0000x reference)
//
#include <hip/hip_runtime.h>

// ---------------- problem constants ----------------
#define NN    10000          // nodes
#define FIN   2000           // input features
#define NH    10             // heads
#define C1    128            // layer-1 out channels per head
#define C2    64             // layer-2 out channels per head
#define HC1   1280           // NH*C1
#define HC2   640            // NH*C2
#define MP    10240          // nodes padded to 128*80 (m-tile swizzle needs full 80 tiles)
#define K1P   2016           // FIN padded to 32 multiple (63*32)

typedef _Float16 f16x8 __attribute__((ext_vector_type(8)));
typedef _Float16 f16x4 __attribute__((ext_vector_type(4)));
typedef _Float16 f16x2 __attribute__((ext_vector_type(2)));
typedef float    f32x4 __attribute__((ext_vector_type(4)));

// ---------------- fp32 -> fp16 cast + pad, float4-vectorized ----------------
__global__ void k_cast_pad4(const float* __restrict__ src, _Float16* __restrict__ dst,
                            int R, int C4, int Cp4) {
    int idx = blockIdx.x * 256 + threadIdx.x;
    int total = MP * Cp4;
    if (idx >= total) return;
    int r = idx / Cp4, c = idx - r * Cp4;
    float4 v = make_float4(0.f, 0.f, 0.f, 0.f);
    if (r < R && c < C4) v = *(const float4*)(src + (long)r * (C4 * 4) + 4 * c);
    f16x4 o = {(_Float16)v.x, (_Float16)v.y, (_Float16)v.z, (_Float16)v.w};
    *(f16x4*)(dst + (long)r * (Cp4 * 4) + 4 * c) = o;
}

// ---------------- zero fp16 pad rows ----------------
__global__ void k_zero_f16(_Float16* __restrict__ p, int count) {
    int i = blockIdx.x * 256 + threadIdx.x;
    if (i < count) p[i] = (_Float16)0.f;
}

// ---------------- W [K][N] -> Wt fp16 [N][Kpad] (zero k-pad) ----------------
__global__ void k_transpose_W(const float* __restrict__ W, _Float16* __restrict__ Wt,
                              int K, int N, int Kpad) {
    __shared__ float tile[32][33];
    int tx = threadIdx.x & 31;
    int ty = threadIdx.x >> 5;           // 0..7
    int kbase = blockIdx.x * 32;
    int nbase = blockIdx.y * 32;
#pragma unroll
    for (int i = 0; i < 4; i++) {
        int k = kbase + ty + i * 8;
        float v = (k < K) ? W[(long)k * N + nbase + tx] : 0.0f;
        tile[ty + i * 8][tx] = v;
    }
    __syncthreads();
#pragma unroll
    for (int i = 0; i < 4; i++) {
        int n = nbase + ty + i * 8;
        Wt[(long)n * Kpad + kbase + tx] = (_Float16)tile[tx][ty + i * 8];
    }
}

// ---------------- fp16 MFMA GEMM, barrier-free direct-to-register K-loop ----------------
// C[MpxN](fp16) = A[MpxK] * Bt[NxK]^T. 128x128 block tile, 4 waves (2x2 of 64x64).
// Fragments loaded straight global->VGPR (operands are L2-resident; XCD-affine
// grid keeps each m-tile's A in one XCD's L2). Register double-buffer, NO LDS,
// NO __syncthreads in the K-loop -> compiler emits fine-grained vmcnt, prefetch
// of k+1 stays in flight across MFMA of k.
__global__ __launch_bounds__(256) void k_gemm(const _Float16* __restrict__ A,
                                              const _Float16* __restrict__ Bt,
                                              _Float16* __restrict__ C, int K, int N,
                                              int NTN) {
    int bid = blockIdx.x;
    int r = bid & 7, qb = bid >> 3;
    int n_t = qb % NTN;
    int m_t = r + 8 * (qb / NTN);     // consecutive qb share m_t's A-tile on one XCD
    int m0 = m_t * 128;
    int n0 = n_t * 128;
    int lane = threadIdx.x & 63, wave = threadIdx.x >> 6;
    int wr = wave >> 1, wc = wave & 1;
    int lrow = lane & 15, q = lane >> 4;

    // per-lane fragment base pointers: A[m=lrow][k=q*8+j], B[n=lrow][k=q*8+j]
    const _Float16* ap[4];
    const _Float16* bp[4];
#pragma unroll
    for (int i = 0; i < 4; i++) {
        ap[i] = A  + (long)(m0 + wr * 64 + i * 16 + lrow) * K + q * 8;
        bp[i] = Bt + (long)(n0 + wc * 64 + i * 16 + lrow) * K + q * 8;
    }

    f32x4 acc[4][4] = {};
    f16x8 ac[4], bc[4];
#pragma unroll
    for (int i = 0; i < 4; i++) { ac[i] = *(const f16x8*)(ap[i]); bc[i] = *(const f16x8*)(bp[i]); }

    int nk = K >> 5;
#pragma unroll 2
    for (int it = 1; it < nk; it++) {
        f16x8 an[4], bn[4];
#pragma unroll
        for (int i = 0; i < 4; i++) {
            an[i] = *(const f16x8*)(ap[i] + it * 32);
            bn[i] = *(const f16x8*)(bp[i] + it * 32);
        }
#pragma unroll
        for (int mt = 0; mt < 4; mt++)
#pragma unroll
            for (int nt = 0; nt < 4; nt++)
                acc[mt][nt] = __builtin_amdgcn_mfma_f32_16x16x32_f16(ac[mt], bc[nt], acc[mt][nt], 0, 0, 0);
#pragma unroll
        for (int i = 0; i < 4; i++) { ac[i] = an[i]; bc[i] = bn[i]; }
    }
#pragma unroll
    for (int mt = 0; mt < 4; mt++)
#pragma unroll
        for (int nt = 0; nt < 4; nt++)
            acc[mt][nt] = __builtin_amdgcn_mfma_f32_16x16x32_f16(ac[mt], bc[nt], acc[mt][nt], 0, 0, 0);

#pragma unroll
    for (int mt = 0; mt < 4; mt++)
#pragma unroll
        for (int nt = 0; nt < 4; nt++)
#pragma unroll
            for (int rr = 0; rr < 4; rr++) {
                int row = m0 + wr * 64 + mt * 16 + q * 4 + rr;
                int colc = n0 + wc * 64 + nt * 16 + lrow;
                C[(long)row * N + colc] = (_Float16)acc[mt][nt][rr];
            }
}

// ---------------- CSR build ----------------
__global__ void k_csr_init(int* counts, int n) {          // self-loop pre-count
    int i = blockIdx.x * 256 + threadIdx.x;
    if (i < n) counts[i] = 1;
}
__global__ void k_csr_count(const int* __restrict__ ei, int* counts, int E) {
    int e = blockIdx.x * 256 + threadIdx.x;
    if (e < E) atomicAdd(&counts[ei[E + e]], 1);
}
__global__ void k_scan(const int* __restrict__ counts, int* rowptr, int* cursor, int n) {
    __shared__ int s[1024];
    int t = threadIdx.x;
    int running = 0;
    for (int base = 0; base < n; base += 1024) {
        int i = base + t;
        int v = (i < n) ? counts[i] : 0;
        s[t] = v;
        __syncthreads();
        for (int off = 1; off < 1024; off <<= 1) {
            int add = (t >= off) ? s[t - off] : 0;
            __syncthreads();
            s[t] += add;
            __syncthreads();
        }
        if (i < n) { int ex = running + s[t] - v; rowptr[i] = ex; cursor[i] = ex; }
        int tot = s[1023];
        __syncthreads();
        running += tot;
    }
    if (t == 0) rowptr[n] = running;
}
__global__ void k_csr_fill(const int* __restrict__ ei, int* cursor, int* colidx, int E, int n) {
    int i = blockIdx.x * 256 + threadIdx.x;
    if (i >= E + n) return;
    int s, d;
    if (i < E) { s = ei[i]; d = ei[E + i]; }
    else       { s = i - E; d = i - E; }
    int pos = atomicAdd(&cursor[d], 1);
    colidx[pos] = s;
}

// ---------------- per-node alpha_src / alpha_dst (fp16 h) ----------------
__global__ void k_alpha(const _Float16* __restrict__ hpre, const float* __restrict__ asrc,
                        const float* __restrict__ adst, float* as, float* ad, int C) {
    int wave = threadIdx.x >> 6, lane = threadIdx.x & 63;
    int n = blockIdx.x;
    for (int h = wave; h < NH; h += 4) {
        float sv = 0.f, dv = 0.f;
        for (int c = lane; c < C; c += 64) {
            float hv = (float)hpre[(long)n * NH * C + h * C + c];
            sv += hv * asrc[h * C + c];
            dv += hv * adst[h * C + c];
        }
        for (int m = 32; m; m >>= 1) { sv += __shfl_xor(sv, m); dv += __shfl_xor(dv, m); }
        if (lane == 0) { as[n * NH + h] = sv; ad[n * NH + h] = dv; }
    }
}

// ---------------- per-dst softmax -> per-edge alpha (CSR order) ----------------
__global__ void k_stats(const int* __restrict__ rowptr, const int* __restrict__ colidx,
                        const float* __restrict__ as, const float* __restrict__ ad,
                        float* __restrict__ alphaE) {
    int wave = threadIdx.x >> 6, lane = threadIdx.x & 63;
    int n = blockIdx.x * 4 + wave;
    if (n >= NN) return;
    int k0 = rowptr[n], deg = rowptr[n + 1] - k0;
    if (deg <= 64) {
        float va[NH];
        if (lane < deg) {
            const float* rp = as + (long)colidx[k0 + lane] * NH;
#pragma unroll
            for (int h = 0; h < NH; h++) va[h] = rp[h];
        }
        const float* adp = ad + n * NH;
        for (int h = 0; h < NH; h++) {
            float adv = adp[h];
            float e = -1e30f;
            if (lane < deg) {
                e = va[h] + adv;
                e = e > 0.f ? e : 0.2f * e;
            }
            float mx = e;
            for (int m = 32; m; m >>= 1) mx = fmaxf(mx, __shfl_xor(mx, m));
            float ex = (lane < deg) ? __expf(e - mx) : 0.f;
            float sum = ex;
            for (int m = 32; m; m >>= 1) sum += __shfl_xor(sum, m);
            if (lane < deg) alphaE[(long)(k0 + lane) * NH + h] = ex / (sum + 1e-16f);
        }
        return;
    }
    for (int h = 0; h < NH; h++) {
        float adv = ad[n * NH + h];
        float mx = -1e30f;
        for (int j = lane; j < deg; j += 64) {
            float e = as[colidx[k0 + j] * NH + h] + adv;
            e = e > 0.f ? e : 0.2f * e;
            mx = fmaxf(mx, e);
        }
        for (int m = 32; m; m >>= 1) mx = fmaxf(mx, __shfl_xor(mx, m));
        float sum = 0.f;
        for (int j = lane; j < deg; j += 64) {
            float e = as[colidx[k0 + j] * NH + h] + adv;
            e = e > 0.f ? e : 0.2f * e;
            sum += __expf(e - mx);
        }
        for (int m = 32; m; m >>= 1) sum += __shfl_xor(sum, m);
        float inv = 1.0f / (sum + 1e-16f);
        for (int j = lane; j < deg; j += 64) {
            float e = as[colidx[k0 + j] * NH + h] + adv;
            e = e > 0.f ? e : 0.2f * e;
            alphaE[(long)(k0 + j) * NH + h] = __expf(e - mx) * inv;
        }
    }
}

// ---------------- layer-1 aggregation (fp16 gather) -> A2 fp16 directly ----------------
__global__ __launch_bounds__(320) void k_agg1(const int* __restrict__ rowptr,
                                              const int* __restrict__ colidx,
                                              const float* __restrict__ alphaE,
                                              const _Float16* __restrict__ h,
                                              const float* __restrict__ bias,
                                              _Float16* __restrict__ A2) {
    __shared__ int sidx[64];
    __shared__ float sal[64 * NH];
    int n = blockIdx.x, t = threadIdx.x;
    int k0 = rowptr[n], deg = rowptr[n + 1] - k0;
    int hd = t >> 5;
    float acc[4] = {0, 0, 0, 0};
    for (int c0 = 0; c0 < deg; c0 += 64) {
        int cn = min(64, deg - c0);
        __syncthreads();
        if (t < cn) sidx[t] = colidx[k0 + c0 + t];
        for (int idx = t; idx < cn * NH; idx += 320) sal[idx] = alphaE[(long)(k0 + c0) * NH + idx];
        __syncthreads();
        for (int j = 0; j < cn; j++) {
            int src = sidx[j];
            float a = sal[j * NH + hd];
            f16x4 v = *(const f16x4*)(h + (long)src * HC1 + 4 * t);
            acc[0] += a * (float)v[0];
            acc[1] += a * (float)v[1];
            acc[2] += a * (float)v[2];
            acc[3] += a * (float)v[3];
        }
    }
    f16x4 o;
#pragma unroll
    for (int i = 0; i < 4; i++) {
        float x = acc[i] + bias[4 * t + i];
        o[i] = (_Float16)(x > 0.f ? x : 0.f);
    }
    *(f16x4*)(A2 + (long)n * HC1 + 4 * t) = o;
}

// ---------------- layer-2 aggregation (fp16 gather) + head mean + bias + relu ----------------
__global__ __launch_bounds__(320) void k_agg2(const int* __restrict__ rowptr,
                                              const int* __restrict__ colidx,
                                              const float* __restrict__ alphaE,
                                              const _Float16* __restrict__ h,
                                              const float* __restrict__ bias,
                                              float* __restrict__ out) {
    __shared__ int sidx[64];
    __shared__ float sal[64 * NH];
    __shared__ float facc[HC2];
    int n = blockIdx.x, t = threadIdx.x;
    int k0 = rowptr[n], deg = rowptr[n + 1] - k0;
    int hd = t >> 5;
    float a0 = 0.f, a1 = 0.f;
    for (int c0 = 0; c0 < deg; c0 += 64) {
        int cn = min(64, deg - c0);
        __syncthreads();
        if (t < cn) sidx[t] = colidx[k0 + c0 + t];
        for (int idx = t; idx < cn * NH; idx += 320) sal[idx] = alphaE[(long)(k0 + c0) * NH + idx];
        __syncthreads();
        for (int j = 0; j < cn; j++) {
            int src = sidx[j];
            float a = sal[j * NH + hd];
            f16x2 v = *(const f16x2*)(h + (long)src * HC2 + 2 * t);
            a0 += a * (float)v[0];
            a1 += a * (float)v[1];
        }
    }
    facc[2 * t] = a0;
    facc[2 * t + 1] = a1;
    __syncthreads();
    if (t < C2) {
        float s = 0.f;
#pragma unroll
        for (int hh = 0; hh < NH; hh++) s += facc[hh * C2 + t];
        s = s * 0.1f + bias[t];
        out[(long)n * C2 + t] = s > 0.f ? s : 0.f;
    }
}

// ---------------- host ----------------
extern "C" void kernel_launch(void* const* d_in, const int* in_sizes, int n_in,
                              void* d_out, int out_size, void* d_ws, size_t ws_size,
                              hipStream_t stream) {
    const float* x      = (const float*)d_in[0];
    const int*   ei     = (const int*)d_in[1];
    const float* W1     = (const float*)d_in[2];
    const float* asrc1  = (const float*)d_in[3];
    const float* adst1  = (const float*)d_in[4];
    const float* b1     = (const float*)d_in[5];
    const float* W2     = (const float*)d_in[6];
    const float* asrc2  = (const float*)d_in[7];
    const float* adst2  = (const float*)d_in[8];
    const float* b2     = (const float*)d_in[9];
    float* out = (float*)d_out;
    const int E  = in_sizes[1] / 2;
    const int EN = E + NN;

    char* base = (char*)d_ws;
    size_t o = 0;
    auto alloc = [&](size_t bytes) { size_t r = o; o += (bytes + 255) & ~(size_t)255; return r; };
    _Float16* A1    = (_Float16*)(base + alloc((size_t)MP * K1P * 2));
    _Float16* W1t   = (_Float16*)(base + alloc((size_t)HC1 * K1P * 2));
    _Float16* A2    = (_Float16*)(base + alloc((size_t)MP * HC1 * 2));
    _Float16* W2t   = (_Float16*)(base + alloc((size_t)HC2 * HC1 * 2));
    _Float16* h1pre = (_Float16*)(base + alloc((size_t)MP * HC1 * 2));
    _Float16* h2pre = (_Float16*)(base + alloc((size_t)MP * HC2 * 2));
    float* as1      = (float*)(base + alloc((size_t)NN * NH * 4));
    float* ad1      = (float*)(base + alloc((size_t)NN * NH * 4));
    float* as2      = (float*)(base + alloc((size_t)NN * NH * 4));
    float* ad2      = (float*)(base + alloc((size_t)NN * NH * 4));
    int* counts     = (int*)(base + alloc((size_t)(NN + 1) * 4));
    int* rowptr     = (int*)(base + alloc((size_t)(NN + 1) * 4));
    int* cursor     = (int*)(base + alloc((size_t)(NN + 1) * 4));
    int* colidx     = (int*)(base + alloc((size_t)EN * 4));
    float* alphaE   = (float*)(base + alloc((size_t)EN * NH * 4));
    (void)ws_size; (void)n_in; (void)out_size;

    // ---- layer 1 GEMM: h1pre(fp16) = x @ W1 ----
    k_cast_pad4<<<(MP * (K1P / 4) + 255) / 256, 256, 0, stream>>>(x, A1, NN, FIN / 4, K1P / 4);
    k_transpose_W<<<dim3(K1P / 32, HC1 / 32), 256, 0, stream>>>(W1, W1t, FIN, HC1, K1P);
    k_gemm<<<8 * (MP / 128 / 8) * (HC1 / 128), 256, 0, stream>>>(A1, W1t, h1pre, K1P, HC1, HC1 / 128);

    // ---- CSR (shared by both layers) ----
    k_csr_init<<<(NN + 255) / 256, 256, 0, stream>>>(counts, NN);
    k_csr_count<<<(E + 255) / 256, 256, 0, stream>>>(ei, counts, E);
    k_scan<<<1, 1024, 0, stream>>>(counts, rowptr, cursor, NN);
    k_csr_fill<<<(EN + 255) / 256, 256, 0, stream>>>(ei, cursor, colidx, E, NN);

    // ---- layer 1 attention + aggregate -> A2 fp16 (bias+relu fused) ----
    k_alpha<<<NN, 256, 0, stream>>>(h1pre, asrc1, adst1, as1, ad1, C1);
    k_stats<<<(NN + 3) / 4, 256, 0, stream>>>(rowptr, colidx, as1, ad1, alphaE);
    k_agg1<<<NN, 320, 0, stream>>>(rowptr, colidx, alphaE, h1pre, b1, A2);
    k_zero_f16<<<((MP - NN) * HC1 + 255) / 256, 256, 0, stream>>>(A2 + (long)NN * HC1, (MP - NN) * HC1);

    // ---- layer 2 GEMM: h2pre(fp16) = A2 @ W2 ----
    k_transpose_W<<<dim3(HC1 / 32, HC2 / 32), 256, 0, stream>>>(W2, W2t, HC1, HC2, HC1);
    k_gemm<<<8 * (MP / 128 / 8) * (HC2 / 128), 256, 0, stream>>>(A2, W2t, h2pre, HC1, HC2, HC2 / 128);

    // ---- layer 2 attention + aggregate (mean heads) ----
    k_alpha<<<NN, 256, 0, stream>>>(h2pre, asrc2, adst2, as2, ad2, C2);
    k_stats<<<(NN + 3) / 4, 256, 0, stream>>>(rowptr, colidx, as2, ad2, alphaE);
    k_agg2<<<NN, 320, 0, stream>>>(rowptr, colidx, alphaE, h2pre, b2, out);
}

// Round 5
// 470.431 us; speedup vs baseline: 1.2581x; 1.2581x over previous
//
#include <hip/hip_runtime.h>

// ---------------- problem constants ----------------
#define NN    10000          // nodes
#define FIN   2000           // input features
#define NH    10             // heads
#define C1    128            // layer-1 out channels per head
#define C2    64             // layer-2 out channels per head
#define HC1   1280           // NH*C1
#define HC2   640            // NH*C2
#define MP    10240          // nodes padded to 128*80 (m-tile swizzle needs full 80 tiles)
#define K1P   2016           // FIN padded to 32 multiple (63*32)

typedef _Float16 f16x8 __attribute__((ext_vector_type(8)));
typedef _Float16 f16x4 __attribute__((ext_vector_type(4)));
typedef _Float16 f16x2 __attribute__((ext_vector_type(2)));
typedef float    f32x4 __attribute__((ext_vector_type(4)));

// ---------------- fp32 -> fp16 cast + pad, float4-vectorized ----------------
__global__ void k_cast_pad4(const float* __restrict__ src, _Float16* __restrict__ dst,
                            int R, int C4, int Cp4) {
    int idx = blockIdx.x * 256 + threadIdx.x;
    int total = MP * Cp4;
    if (idx >= total) return;
    int r = idx / Cp4, c = idx - r * Cp4;
    float4 v = make_float4(0.f, 0.f, 0.f, 0.f);
    if (r < R && c < C4) v = *(const float4*)(src + (long)r * (C4 * 4) + 4 * c);
    f16x4 o = {(_Float16)v.x, (_Float16)v.y, (_Float16)v.z, (_Float16)v.w};
    *(f16x4*)(dst + (long)r * (Cp4 * 4) + 4 * c) = o;
}

// ---------------- zero fp16 pad rows ----------------
__global__ void k_zero_f16(_Float16* __restrict__ p, int count) {
    int i = blockIdx.x * 256 + threadIdx.x;
    if (i < count) p[i] = (_Float16)0.f;
}

// ---------------- W [K][N] -> Wt fp16 [N][Kpad] (zero k-pad) ----------------
__global__ void k_transpose_W(const float* __restrict__ W, _Float16* __restrict__ Wt,
                              int K, int N, int Kpad) {
    __shared__ float tile[32][33];
    int tx = threadIdx.x & 31;
    int ty = threadIdx.x >> 5;           // 0..7
    int kbase = blockIdx.x * 32;
    int nbase = blockIdx.y * 32;
#pragma unroll
    for (int i = 0; i < 4; i++) {
        int k = kbase + ty + i * 8;
        float v = (k < K) ? W[(long)k * N + nbase + tx] : 0.0f;
        tile[ty + i * 8][tx] = v;
    }
    __syncthreads();
#pragma unroll
    for (int i = 0; i < 4; i++) {
        int n = nbase + ty + i * 8;
        Wt[(long)n * Kpad + kbase + tx] = (_Float16)tile[tx][ty + i * 8];
    }
}

// ---------------- async global->LDS helper ----------------
__device__ __forceinline__ void gl2lds16(const void* g, void* l) {
    __builtin_amdgcn_global_load_lds((const __attribute__((address_space(1))) void*)g,
                                     (__attribute__((address_space(3))) void*)l, 16, 0, 0);
}

// s_waitcnt immediates (gfx9 encoding: vmcnt[3:0] | expcnt<<4 | lgkmcnt<<8 | vmcnt[5:4]<<14)
#define WAITCNT_VM4  0x0F74   // vmcnt<=4, lgkm/exp don't-care
#define WAITCNT_VM0  0x0F70   // vmcnt==0

// ---------------- fp16 MFMA GEMM: C[MpxN](fp16) = A[MpxK] * Bt[NxK]^T ----------------
// 128x128 tile, 4 waves, 16x16x32 MFMA, XOR quad-swizzled LDS.
// Depth-2 software pipeline: tri-buffered LDS, raw s_barrier + s_waitcnt vmcnt(4)
// so the k+1 staging stays IN FLIGHT across the barrier (never drain to zero).
// XCD-affine grid: bid&7 selects m-group so same-A blocks share one XCD's L2.
__global__ __launch_bounds__(256) void k_gemm(const _Float16* __restrict__ A,
                                              const _Float16* __restrict__ Bt,
                                              _Float16* __restrict__ C, int K, int N,
                                              int NTN) {
    __shared__ char smem[49152] __attribute__((aligned(16)));
    _Float16* As = (_Float16*)smem;             // 3 x 4096 fp16 (8KB each)
    _Float16* Bs = (_Float16*)(smem + 24576);   // 3 x 4096 fp16

    int bid = blockIdx.x;
    int r = bid & 7, qb = bid >> 3;
    int n_t = qb % NTN;
    int m_t = r + 8 * (qb / NTN);     // consecutive qb share m_t's A-tile on one XCD
    int m0 = m_t * 128;
    int n0 = n_t * 128;
    int t = threadIdx.x;
    int lane = t & 63, wave = t >> 6;
    int wr = wave >> 1, wc = wave & 1;
    int lrow = lane & 15, q = lane >> 4;

    f32x4 acc[4][4] = {};

    // staging: slot s (0..511): m_slot=s>>2, quad_slot=s&3, swizzled global quad
    int s0 = t, s1 = t + 256;
    int am0 = s0 >> 2, aq0 = (s0 & 3) ^ ((s0 >> 3) & 3);
    int am1 = s1 >> 2, aq1 = (s1 & 3) ^ ((s1 >> 3) & 3);
    const _Float16* Ar0 = A + (long)(m0 + am0) * K + aq0 * 8;
    const _Float16* Ar1 = A + (long)(m0 + am1) * K + aq1 * 8;
    const _Float16* Br0 = Bt + (long)(n0 + am0) * K + aq0 * 8;
    const _Float16* Br1 = Bt + (long)(n0 + am1) * K + aq1 * 8;

    int aoff[4], boff[4];
#pragma unroll
    for (int i = 0; i < 4; i++) {
        int rowa = wr * 64 + i * 16 + lrow;
        aoff[i] = rowa * 32 + ((q ^ ((rowa >> 1) & 3)) << 3);
        int rowb = wc * 64 + i * 16 + lrow;
        boff[i] = rowb * 32 + ((q ^ ((rowb >> 1) & 3)) << 3);
    }

    auto stage = [&](int it, int buf) {
        int k0 = it << 5;
        gl2lds16(Ar0 + k0, &As[buf * 4096 + s0 * 8]);
        gl2lds16(Ar1 + k0, &As[buf * 4096 + s1 * 8]);
        gl2lds16(Br0 + k0, &Bs[buf * 4096 + s0 * 8]);
        gl2lds16(Br1 + k0, &Bs[buf * 4096 + s1 * 8]);
    };

    int nk = K >> 5;
    stage(0, 0);            // 4 loads in flight
    stage(1, 1);            // 8 in flight
    int cur = 0;
    for (int it = 0; it < nk; it++) {
        // wait for stage(it) only: newest 4 loads (stage(it+1)) may stay in flight
        if (it + 1 < nk) __builtin_amdgcn_s_waitcnt(WAITCNT_VM4);
        else             __builtin_amdgcn_s_waitcnt(WAITCNT_VM0);
        __builtin_amdgcn_s_barrier();   // buf[cur] staged everywhere; buf[cur+2] reads all done
        int nxt = cur + 2; if (nxt >= 3) nxt -= 3;
        if (it + 2 < nk) stage(it + 2, nxt);

        f16x8 af[4], bf[4];
#pragma unroll
        for (int i = 0; i < 4; i++) {
            af[i] = *(const f16x8*)&As[cur * 4096 + aoff[i]];
            bf[i] = *(const f16x8*)&Bs[cur * 4096 + boff[i]];
        }
#pragma unroll
        for (int mt = 0; mt < 4; mt++)
#pragma unroll
            for (int nt = 0; nt < 4; nt++)
                acc[mt][nt] = __builtin_amdgcn_mfma_f32_16x16x32_f16(af[mt], bf[nt], acc[mt][nt], 0, 0, 0);
        cur = (cur + 1 == 3) ? 0 : cur + 1;
    }

    // ---- epilogue: repack through LDS for coalesced 16B stores ----
    __syncthreads();                    // all waves done reading As/Bs
    _Float16* Cs = (_Float16*)smem;     // 128 x 152 fp16 = 38,912 B (152: 16B-aligned rows, conflict-free)
#pragma unroll
    for (int mt = 0; mt < 4; mt++)
#pragma unroll
        for (int nt = 0; nt < 4; nt++)
#pragma unroll
            for (int rr = 0; rr < 4; rr++) {
                int rl = wr * 64 + mt * 16 + q * 4 + rr;
                int cl = wc * 64 + nt * 16 + lrow;
                Cs[rl * 152 + cl] = (_Float16)acc[mt][nt][rr];
            }
    __syncthreads();
    {
        int r2 = t >> 1, half = t & 1;
        const f16x8* srcp = (const f16x8*)&Cs[r2 * 152 + half * 64];
        _Float16* dstp = C + (long)(m0 + r2) * N + n0 + half * 64;
#pragma unroll
        for (int i = 0; i < 8; i++)
            *(f16x8*)(dstp + i * 8) = srcp[i];
    }
}

// ---------------- CSR build ----------------
__global__ void k_csr_init(int* counts, int n) {          // self-loop pre-count
    int i = blockIdx.x * 256 + threadIdx.x;
    if (i < n) counts[i] = 1;
}
__global__ void k_csr_count(const int* __restrict__ ei, int* counts, int E) {
    int e = blockIdx.x * 256 + threadIdx.x;
    if (e < E) atomicAdd(&counts[ei[E + e]], 1);
}
__global__ void k_scan(const int* __restrict__ counts, int* rowptr, int* cursor, int n) {
    __shared__ int s[1024];
    int t = threadIdx.x;
    int running = 0;
    for (int base = 0; base < n; base += 1024) {
        int i = base + t;
        int v = (i < n) ? counts[i] : 0;
        s[t] = v;
        __syncthreads();
        for (int off = 1; off < 1024; off <<= 1) {
            int add = (t >= off) ? s[t - off] : 0;
            __syncthreads();
            s[t] += add;
            __syncthreads();
        }
        if (i < n) { int ex = running + s[t] - v; rowptr[i] = ex; cursor[i] = ex; }
        int tot = s[1023];
        __syncthreads();
        running += tot;
    }
    if (t == 0) rowptr[n] = running;
}
__global__ void k_csr_fill(const int* __restrict__ ei, int* cursor, int* colidx, int E, int n) {
    int i = blockIdx.x * 256 + threadIdx.x;
    if (i >= E + n) return;
    int s, d;
    if (i < E) { s = ei[i]; d = ei[E + i]; }
    else       { s = i - E; d = i - E; }
    int pos = atomicAdd(&cursor[d], 1);
    colidx[pos] = s;
}

// ---------------- per-node alpha_src / alpha_dst (fp16 h) ----------------
__global__ void k_alpha(const _Float16* __restrict__ hpre, const float* __restrict__ asrc,
                        const float* __restrict__ adst, float* as, float* ad, int C) {
    int wave = threadIdx.x >> 6, lane = threadIdx.x & 63;
    int n = blockIdx.x;
    for (int h = wave; h < NH; h += 4) {
        float sv = 0.f, dv = 0.f;
        for (int c = lane; c < C; c += 64) {
            float hv = (float)hpre[(long)n * NH * C + h * C + c];
            sv += hv * asrc[h * C + c];
            dv += hv * adst[h * C + c];
        }
        for (int m = 32; m; m >>= 1) { sv += __shfl_xor(sv, m); dv += __shfl_xor(dv, m); }
        if (lane == 0) { as[n * NH + h] = sv; ad[n * NH + h] = dv; }
    }
}

// ---------------- per-dst softmax -> per-edge alpha (CSR order) ----------------
__global__ void k_stats(const int* __restrict__ rowptr, const int* __restrict__ colidx,
                        const float* __restrict__ as, const float* __restrict__ ad,
                        float* __restrict__ alphaE) {
    int wave = threadIdx.x >> 6, lane = threadIdx.x & 63;
    int n = blockIdx.x * 4 + wave;
    if (n >= NN) return;
    int k0 = rowptr[n], deg = rowptr[n + 1] - k0;
    if (deg <= 64) {
        float va[NH];
        if (lane < deg) {
            const float* rp = as + (long)colidx[k0 + lane] * NH;
#pragma unroll
            for (int h = 0; h < NH; h++) va[h] = rp[h];
        }
        const float* adp = ad + n * NH;
        for (int h = 0; h < NH; h++) {
            float adv = adp[h];
            float e = -1e30f;
            if (lane < deg) {
                e = va[h] + adv;
                e = e > 0.f ? e : 0.2f * e;
            }
            float mx = e;
            for (int m = 32; m; m >>= 1) mx = fmaxf(mx, __shfl_xor(mx, m));
            float ex = (lane < deg) ? __expf(e - mx) : 0.f;
            float sum = ex;
            for (int m = 32; m; m >>= 1) sum += __shfl_xor(sum, m);
            if (lane < deg) alphaE[(long)(k0 + lane) * NH + h] = ex / (sum + 1e-16f);
        }
        return;
    }
    for (int h = 0; h < NH; h++) {
        float adv = ad[n * NH + h];
        float mx = -1e30f;
        for (int j = lane; j < deg; j += 64) {
            float e = as[colidx[k0 + j] * NH + h] + adv;
            e = e > 0.f ? e : 0.2f * e;
            mx = fmaxf(mx, e);
        }
        for (int m = 32; m; m >>= 1) mx = fmaxf(mx, __shfl_xor(mx, m));
        float sum = 0.f;
        for (int j = lane; j < deg; j += 64) {
            float e = as[colidx[k0 + j] * NH + h] + adv;
            e = e > 0.f ? e : 0.2f * e;
            sum += __expf(e - mx);
        }
        for (int m = 32; m; m >>= 1) sum += __shfl_xor(sum, m);
        float inv = 1.0f / (sum + 1e-16f);
        for (int j = lane; j < deg; j += 64) {
            float e = as[colidx[k0 + j] * NH + h] + adv;
            e = e > 0.f ? e : 0.2f * e;
            alphaE[(long)(k0 + j) * NH + h] = __expf(e - mx) * inv;
        }
    }
}

// ---------------- layer-1 aggregation (fp16 gather) -> A2 fp16 directly ----------------
__global__ __launch_bounds__(320) void k_agg1(const int* __restrict__ rowptr,
                                              const int* __restrict__ colidx,
                                              const float* __restrict__ alphaE,
                                              const _Float16* __restrict__ h,
                                              const float* __restrict__ bias,
                                              _Float16* __restrict__ A2) {
    __shared__ int sidx[64];
    __shared__ float sal[64 * NH];
    int n = blockIdx.x, t = threadIdx.x;
    int k0 = rowptr[n], deg = rowptr[n + 1] - k0;
    int hd = t >> 5;
    float acc[4] = {0, 0, 0, 0};
    for (int c0 = 0; c0 < deg; c0 += 64) {
        int cn = min(64, deg - c0);
        __syncthreads();
        if (t < cn) sidx[t] = colidx[k0 + c0 + t];
        for (int idx = t; idx < cn * NH; idx += 320) sal[idx] = alphaE[(long)(k0 + c0) * NH + idx];
        __syncthreads();
        for (int j = 0; j < cn; j++) {
            int src = sidx[j];
            float a = sal[j * NH + hd];
            f16x4 v = *(const f16x4*)(h + (long)src * HC1 + 4 * t);
            acc[0] += a * (float)v[0];
            acc[1] += a * (float)v[1];
            acc[2] += a * (float)v[2];
            acc[3] += a * (float)v[3];
        }
    }
    f16x4 o;
#pragma unroll
    for (int i = 0; i < 4; i++) {
        float x = acc[i] + bias[4 * t + i];
        o[i] = (_Float16)(x > 0.f ? x : 0.f);
    }
    *(f16x4*)(A2 + (long)n * HC1 + 4 * t) = o;
}

// ---------------- layer-2 aggregation (fp16 gather) + head mean + bias + relu ----------------
__global__ __launch_bounds__(320) void k_agg2(const int* __restrict__ rowptr,
                                              const int* __restrict__ colidx,
                                              const float* __restrict__ alphaE,
                                              const _Float16* __restrict__ h,
                                              const float* __restrict__ bias,
                                              float* __restrict__ out) {
    __shared__ int sidx[64];
    __shared__ float sal[64 * NH];
    __shared__ float facc[HC2];
    int n = blockIdx.x, t = threadIdx.x;
    int k0 = rowptr[n], deg = rowptr[n + 1] - k0;
    int hd = t >> 5;
    float a0 = 0.f, a1 = 0.f;
    for (int c0 = 0; c0 < deg; c0 += 64) {
        int cn = min(64, deg - c0);
        __syncthreads();
        if (t < cn) sidx[t] = colidx[k0 + c0 + t];
        for (int idx = t; idx < cn * NH; idx += 320) sal[idx] = alphaE[(long)(k0 + c0) * NH + idx];
        __syncthreads();
        for (int j = 0; j < cn; j++) {
            int src = sidx[j];
            float a = sal[j * NH + hd];
            f16x2 v = *(const f16x2*)(h + (long)src * HC2 + 2 * t);
            a0 += a * (float)v[0];
            a1 += a * (float)v[1];
        }
    }
    facc[2 * t] = a0;
    facc[2 * t + 1] = a1;
    __syncthreads();
    if (t < C2) {
        float s = 0.f;
#pragma unroll
        for (int hh = 0; hh < NH; hh++) s += facc[hh * C2 + t];
        s = s * 0.1f + bias[t];
        out[(long)n * C2 + t] = s > 0.f ? s : 0.f;
    }
}

// ---------------- host ----------------
extern "C" void kernel_launch(void* const* d_in, const int* in_sizes, int n_in,
                              void* d_out, int out_size, void* d_ws, size_t ws_size,
                              hipStream_t stream) {
    const float* x      = (const float*)d_in[0];
    const int*   ei     = (const int*)d_in[1];
    const float* W1     = (const float*)d_in[2];
    const float* asrc1  = (const float*)d_in[3];
    const float* adst1  = (const float*)d_in[4];
    const float* b1     = (const float*)d_in[5];
    const float* W2     = (const float*)d_in[6];
    const float* asrc2  = (const float*)d_in[7];
    const float* adst2  = (const float*)d_in[8];
    const float* b2     = (const float*)d_in[9];
    float* out = (float*)d_out;
    const int E  = in_sizes[1] / 2;
    const int EN = E + NN;

    char* base = (char*)d_ws;
    size_t o = 0;
    auto alloc = [&](size_t bytes) { size_t r = o; o += (bytes + 255) & ~(size_t)255; return r; };
    _Float16* A1    = (_Float16*)(base + alloc((size_t)MP * K1P * 2));
    _Float16* W1t   = (_Float16*)(base + alloc((size_t)HC1 * K1P * 2));
    _Float16* A2    = (_Float16*)(base + alloc((size_t)MP * HC1 * 2));
    _Float16* W2t   = (_Float16*)(base + alloc((size_t)HC2 * HC1 * 2));
    _Float16* h1pre = (_Float16*)(base + alloc((size_t)MP * HC1 * 2));
    _Float16* h2pre = (_Float16*)(base + alloc((size_t)MP * HC2 * 2));
    float* as1      = (float*)(base + alloc((size_t)NN * NH * 4));
    float* ad1      = (float*)(base + alloc((size_t)NN * NH * 4));
    float* as2      = (float*)(base + alloc((size_t)NN * NH * 4));
    float* ad2      = (float*)(base + alloc((size_t)NN * NH * 4));
    int* counts     = (int*)(base + alloc((size_t)(NN + 1) * 4));
    int* rowptr     = (int*)(base + alloc((size_t)(NN + 1) * 4));
    int* cursor     = (int*)(base + alloc((size_t)(NN + 1) * 4));
    int* colidx     = (int*)(base + alloc((size_t)EN * 4));
    float* alphaE   = (float*)(base + alloc((size_t)EN * NH * 4));
    (void)ws_size; (void)n_in; (void)out_size;

    // ---- layer 1 GEMM: h1pre(fp16) = x @ W1 ----
    k_cast_pad4<<<(MP * (K1P / 4) + 255) / 256, 256, 0, stream>>>(x, A1, NN, FIN / 4, K1P / 4);
    k_transpose_W<<<dim3(K1P / 32, HC1 / 32), 256, 0, stream>>>(W1, W1t, FIN, HC1, K1P);
    k_gemm<<<8 * (MP / 128 / 8) * (HC1 / 128), 256, 0, stream>>>(A1, W1t, h1pre, K1P, HC1, HC1 / 128);

    // ---- CSR (shared by both layers) ----
    k_csr_init<<<(NN + 255) / 256, 256, 0, stream>>>(counts, NN);
    k_csr_count<<<(E + 255) / 256, 256, 0, stream>>>(ei, counts, E);
    k_scan<<<1, 1024, 0, stream>>>(counts, rowptr, cursor, NN);
    k_csr_fill<<<(EN + 255) / 256, 256, 0, stream>>>(ei, cursor, colidx, E, NN);

    // ---- layer 1 attention + aggregate -> A2 fp16 (bias+relu fused) ----
    k_alpha<<<NN, 256, 0, stream>>>(h1pre, asrc1, adst1, as1, ad1, C1);
    k_stats<<<(NN + 3) / 4, 256, 0, stream>>>(rowptr, colidx, as1, ad1, alphaE);
    k_agg1<<<NN, 320, 0, stream>>>(rowptr, colidx, alphaE, h1pre, b1, A2);
    k_zero_f16<<<((MP - NN) * HC1 + 255) / 256, 256, 0, stream>>>(A2 + (long)NN * HC1, (MP - NN) * HC1);

    // ---- layer 2 GEMM: h2pre(fp16) = A2 @ W2 ----
    k_transpose_W<<<dim3(HC1 / 32, HC2 / 32), 256, 0, stream>>>(W2, W2t, HC1, HC2, HC1);
    k_gemm<<<8 * (MP / 128 / 8) * (HC2 / 128), 256, 0, stream>>>(A2, W2t, h2pre, HC1, HC2, HC2 / 128);

    // ---- layer 2 attention + aggregate (mean heads) ----
    k_alpha<<<NN, 256, 0, stream>>>(h2pre, asrc2, adst2, as2, ad2, C2);
    k_stats<<<(NN + 3) / 4, 256, 0, stream>>>(rowptr, colidx, as2, ad2, alphaE);
    k_agg2<<<NN, 320, 0, stream>>>(rowptr, colidx, alphaE, h2pre, b2, out);
}

// Round 6
// 452.805 us; speedup vs baseline: 1.3071x; 1.0389x over previous
//
#include <hip/hip_runtime.h>

// ---------------- problem constants ----------------
#define NN    10000          // nodes
#define FIN   2000           // input features
#define NH    10             // heads
#define C1    128            // layer-1 out channels per head
#define C2    64             // layer-2 out channels per head
#define HC1   1280           // NH*C1
#define HC2   640            // NH*C2
#define MP    10240          // nodes padded to 256*40 (BM=256 tiles, XCD swizzle needs 40 m-tiles)
#define K1P   2016           // FIN padded to 32 multiple (63*32)

typedef _Float16 f16x8 __attribute__((ext_vector_type(8)));
typedef _Float16 f16x4 __attribute__((ext_vector_type(4)));
typedef _Float16 f16x2 __attribute__((ext_vector_type(2)));
typedef float    f32x4 __attribute__((ext_vector_type(4)));

// ---------------- fp32 -> fp16 cast + pad, float4-vectorized ----------------
__global__ void k_cast_pad4(const float* __restrict__ src, _Float16* __restrict__ dst,
                            int R, int C4, int Cp4) {
    int idx = blockIdx.x * 256 + threadIdx.x;
    int total = MP * Cp4;
    if (idx >= total) return;
    int r = idx / Cp4, c = idx - r * Cp4;
    float4 v = make_float4(0.f, 0.f, 0.f, 0.f);
    if (r < R && c < C4) v = *(const float4*)(src + (long)r * (C4 * 4) + 4 * c);
    f16x4 o = {(_Float16)v.x, (_Float16)v.y, (_Float16)v.z, (_Float16)v.w};
    *(f16x4*)(dst + (long)r * (Cp4 * 4) + 4 * c) = o;
}

// ---------------- zero fp16 pad rows ----------------
__global__ void k_zero_f16(_Float16* __restrict__ p, int count) {
    int i = blockIdx.x * 256 + threadIdx.x;
    if (i < count) p[i] = (_Float16)0.f;
}

// ---------------- W [K][N] -> Wt fp16 [N][Kpad] (zero k-pad) ----------------
__global__ void k_transpose_W(const float* __restrict__ W, _Float16* __restrict__ Wt,
                              int K, int N, int Kpad) {
    __shared__ float tile[32][33];
    int tx = threadIdx.x & 31;
    int ty = threadIdx.x >> 5;           // 0..7
    int kbase = blockIdx.x * 32;
    int nbase = blockIdx.y * 32;
#pragma unroll
    for (int i = 0; i < 4; i++) {
        int k = kbase + ty + i * 8;
        float v = (k < K) ? W[(long)k * N + nbase + tx] : 0.0f;
        tile[ty + i * 8][tx] = v;
    }
    __syncthreads();
#pragma unroll
    for (int i = 0; i < 4; i++) {
        int n = nbase + ty + i * 8;
        Wt[(long)n * Kpad + kbase + tx] = (_Float16)tile[tx][ty + i * 8];
    }
}

// ---------------- async global->LDS helper ----------------
__device__ __forceinline__ void gl2lds16(const void* g, void* l) {
    __builtin_amdgcn_global_load_lds((const __attribute__((address_space(1))) void*)g,
                                     (__attribute__((address_space(3))) void*)l, 16, 0, 0);
}

// s_waitcnt immediates (gfx9 encoding: vmcnt[3:0] | expcnt<<4 | lgkmcnt<<8 | vmcnt[5:4]<<14)
#define WAITCNT_VM6  0x0F76   // vmcnt<=6 (one 6-load stage may remain in flight)
#define WAITCNT_VM0  0x0F70   // vmcnt==0

// ---------------- fp16 MFMA GEMM: C[MpxN](fp16) = A[MpxK] * Bt[NxK]^T ----------------
// BM=256 x BN=128 block tile, 4 waves (2x2), wave tile 128x64 (8x4 fragments,
// 128 acc VGPRs) -> 2x FLOP per LDS byte vs 64x64. Tri-buffered LDS with raw
// s_barrier + s_waitcnt vmcnt(6): k+1 staging stays in flight across barriers.
// MFMA computes C^T fragments (operand swap) so each lane holds 4 consecutive
// C-columns of one row -> direct packed f16x4 stores, no LDS repack.
// XCD-affine grid: bid&7 selects m-group so same-A blocks share one XCD's L2.
__global__ __launch_bounds__(256, 2) void k_gemm(const _Float16* __restrict__ A,
                                                 const _Float16* __restrict__ Bt,
                                                 _Float16* __restrict__ C, int K, int N,
                                                 int NTN) {
    __shared__ char smem[73728] __attribute__((aligned(16)));
    _Float16* As = (_Float16*)smem;             // 3 x 8192 fp16 (16KB each)
    _Float16* Bs = (_Float16*)(smem + 49152);   // 3 x 4096 fp16 (8KB each)

    int bid = blockIdx.x;
    int r = bid & 7, qb = bid >> 3;
    int n_t = qb % NTN;
    int m_t = r + 8 * (qb / NTN);     // consecutive qb share m_t's A-tile on one XCD
    int m0 = m_t * 256;
    int n0 = n_t * 128;
    int t = threadIdx.x;
    int lane = t & 63, wave = t >> 6;
    int wr = wave >> 1, wc = wave & 1;
    int lrow = lane & 15, q = lane >> 4;

    f32x4 acc[8][4] = {};

    // staging slots: slot s -> row=s>>2, LDS quad-pos=s&3 holds global quad (s&3)^((row>>1)&3)
    int sA[4], sB[2];
#pragma unroll
    for (int i = 0; i < 4; i++) sA[i] = t + 256 * i;      // 1024 A slots (256 rows)
#pragma unroll
    for (int i = 0; i < 2; i++) sB[i] = t + 256 * i;      // 512 B slots (128 rows)
    const _Float16* Ar[4];
    const _Float16* Br[2];
#pragma unroll
    for (int i = 0; i < 4; i++) {
        int row = sA[i] >> 2, gq = (sA[i] & 3) ^ ((sA[i] >> 3) & 3);
        Ar[i] = A + (long)(m0 + row) * K + gq * 8;
    }
#pragma unroll
    for (int i = 0; i < 2; i++) {
        int row = sB[i] >> 2, gq = (sB[i] & 3) ^ ((sB[i] >> 3) & 3);
        Br[i] = Bt + (long)(n0 + row) * K + gq * 8;
    }

    int aoff[8], boff[4];
#pragma unroll
    for (int i = 0; i < 8; i++) {
        int rowa = wr * 128 + i * 16 + lrow;
        aoff[i] = rowa * 32 + ((q ^ ((rowa >> 1) & 3)) << 3);
    }
#pragma unroll
    for (int i = 0; i < 4; i++) {
        int rowb = wc * 64 + i * 16 + lrow;
        boff[i] = rowb * 32 + ((q ^ ((rowb >> 1) & 3)) << 3);
    }

    auto stage = [&](int it, int buf) {
        int k0 = it << 5;
#pragma unroll
        for (int i = 0; i < 4; i++) gl2lds16(Ar[i] + k0, &As[buf * 8192 + sA[i] * 8]);
#pragma unroll
        for (int i = 0; i < 2; i++) gl2lds16(Br[i] + k0, &Bs[buf * 4096 + sB[i] * 8]);
    };

    int nk = K >> 5;
    stage(0, 0);            // 6 loads in flight
    stage(1, 1);            // 12 in flight
    int cur = 0;
    for (int it = 0; it < nk; it++) {
        // wait for stage(it) only: stage(it+1)'s 6 loads may stay in flight
        if (it + 1 < nk) __builtin_amdgcn_s_waitcnt(WAITCNT_VM6);
        else             __builtin_amdgcn_s_waitcnt(WAITCNT_VM0);
        __builtin_amdgcn_s_barrier();   // buf[cur] staged everywhere; buf[cur+2] reads done
        int nxt = cur + 2; if (nxt >= 3) nxt -= 3;
        if (it + 2 < nk) stage(it + 2, nxt);

        f16x8 af[8], bf[4];
#pragma unroll
        for (int i = 0; i < 8; i++) af[i] = *(const f16x8*)&As[cur * 8192 + aoff[i]];
#pragma unroll
        for (int i = 0; i < 4; i++) bf[i] = *(const f16x8*)&Bs[cur * 4096 + boff[i]];
#pragma unroll
        for (int mt = 0; mt < 8; mt++)
#pragma unroll
            for (int nt = 0; nt < 4; nt++)
                // operand swap: D = Bt_frag x A_frag^T = C^T fragment
                acc[mt][nt] = __builtin_amdgcn_mfma_f32_16x16x32_f16(bf[nt], af[mt], acc[mt][nt], 0, 0, 0);
        cur = (cur + 1 == 3) ? 0 : cur + 1;
    }

    // ---- epilogue: lane holds C[m][n..n+3] per fragment -> packed 8B stores ----
#pragma unroll
    for (int mt = 0; mt < 8; mt++) {
        int m = m0 + wr * 128 + mt * 16 + lrow;
#pragma unroll
        for (int nt = 0; nt < 4; nt++) {
            int n = n0 + wc * 64 + nt * 16 + q * 4;
            f16x4 o = {(_Float16)acc[mt][nt][0], (_Float16)acc[mt][nt][1],
                       (_Float16)acc[mt][nt][2], (_Float16)acc[mt][nt][3]};
            *(f16x4*)(C + (long)m * N + n) = o;
        }
    }
}

// ---------------- CSR build ----------------
__global__ void k_csr_init(int* counts, int n) {          // self-loop pre-count
    int i = blockIdx.x * 256 + threadIdx.x;
    if (i < n) counts[i] = 1;
}
__global__ void k_csr_count(const int* __restrict__ ei, int* counts, int E) {
    int e = blockIdx.x * 256 + threadIdx.x;
    if (e < E) atomicAdd(&counts[ei[E + e]], 1);
}
__global__ void k_scan(const int* __restrict__ counts, int* rowptr, int* cursor, int n) {
    __shared__ int s[1024];
    int t = threadIdx.x;
    int running = 0;
    for (int base = 0; base < n; base += 1024) {
        int i = base + t;
        int v = (i < n) ? counts[i] : 0;
        s[t] = v;
        __syncthreads();
        for (int off = 1; off < 1024; off <<= 1) {
            int add = (t >= off) ? s[t - off] : 0;
            __syncthreads();
            s[t] += add;
            __syncthreads();
        }
        if (i < n) { int ex = running + s[t] - v; rowptr[i] = ex; cursor[i] = ex; }
        int tot = s[1023];
        __syncthreads();
        running += tot;
    }
    if (t == 0) rowptr[n] = running;
}
__global__ void k_csr_fill(const int* __restrict__ ei, int* cursor, int* colidx, int E, int n) {
    int i = blockIdx.x * 256 + threadIdx.x;
    if (i >= E + n) return;
    int s, d;
    if (i < E) { s = ei[i]; d = ei[E + i]; }
    else       { s = i - E; d = i - E; }
    int pos = atomicAdd(&cursor[d], 1);
    colidx[pos] = s;
}

// ---------------- per-node alpha_src / alpha_dst (fp16 h) ----------------
__global__ void k_alpha(const _Float16* __restrict__ hpre, const float* __restrict__ asrc,
                        const float* __restrict__ adst, float* as, float* ad, int C) {
    int wave = threadIdx.x >> 6, lane = threadIdx.x & 63;
    int n = blockIdx.x;
    for (int h = wave; h < NH; h += 4) {
        float sv = 0.f, dv = 0.f;
        for (int c = lane; c < C; c += 64) {
            float hv = (float)hpre[(long)n * NH * C + h * C + c];
            sv += hv * asrc[h * C + c];
            dv += hv * adst[h * C + c];
        }
        for (int m = 32; m; m >>= 1) { sv += __shfl_xor(sv, m); dv += __shfl_xor(dv, m); }
        if (lane == 0) { as[n * NH + h] = sv; ad[n * NH + h] = dv; }
    }
}

// ---------------- per-dst softmax -> per-edge alpha (CSR order) ----------------
__global__ void k_stats(const int* __restrict__ rowptr, const int* __restrict__ colidx,
                        const float* __restrict__ as, const float* __restrict__ ad,
                        float* __restrict__ alphaE) {
    int wave = threadIdx.x >> 6, lane = threadIdx.x & 63;
    int n = blockIdx.x * 4 + wave;
    if (n >= NN) return;
    int k0 = rowptr[n], deg = rowptr[n + 1] - k0;
    if (deg <= 64) {
        float va[NH];
        if (lane < deg) {
            const float* rp = as + (long)colidx[k0 + lane] * NH;
#pragma unroll
            for (int h = 0; h < NH; h++) va[h] = rp[h];
        }
        const float* adp = ad + n * NH;
        for (int h = 0; h < NH; h++) {
            float adv = adp[h];
            float e = -1e30f;
            if (lane < deg) {
                e = va[h] + adv;
                e = e > 0.f ? e : 0.2f * e;
            }
            float mx = e;
            for (int m = 32; m; m >>= 1) mx = fmaxf(mx, __shfl_xor(mx, m));
            float ex = (lane < deg) ? __expf(e - mx) : 0.f;
            float sum = ex;
            for (int m = 32; m; m >>= 1) sum += __shfl_xor(sum, m);
            if (lane < deg) alphaE[(long)(k0 + lane) * NH + h] = ex / (sum + 1e-16f);
        }
        return;
    }
    for (int h = 0; h < NH; h++) {
        float adv = ad[n * NH + h];
        float mx = -1e30f;
        for (int j = lane; j < deg; j += 64) {
            float e = as[colidx[k0 + j] * NH + h] + adv;
            e = e > 0.f ? e : 0.2f * e;
            mx = fmaxf(mx, e);
        }
        for (int m = 32; m; m >>= 1) mx = fmaxf(mx, __shfl_xor(mx, m));
        float sum = 0.f;
        for (int j = lane; j < deg; j += 64) {
            float e = as[colidx[k0 + j] * NH + h] + adv;
            e = e > 0.f ? e : 0.2f * e;
            sum += __expf(e - mx);
        }
        for (int m = 32; m; m >>= 1) sum += __shfl_xor(sum, m);
        float inv = 1.0f / (sum + 1e-16f);
        for (int j = lane; j < deg; j += 64) {
            float e = as[colidx[k0 + j] * NH + h] + adv;
            e = e > 0.f ? e : 0.2f * e;
            alphaE[(long)(k0 + j) * NH + h] = __expf(e - mx) * inv;
        }
    }
}

// ---------------- layer-1 aggregation (fp16 gather) -> A2 fp16 directly ----------------
__global__ __launch_bounds__(320) void k_agg1(const int* __restrict__ rowptr,
                                              const int* __restrict__ colidx,
                                              const float* __restrict__ alphaE,
                                              const _Float16* __restrict__ h,
                                              const float* __restrict__ bias,
                                              _Float16* __restrict__ A2) {
    __shared__ int sidx[64];
    __shared__ float sal[64 * NH];
    int n = blockIdx.x, t = threadIdx.x;
    int k0 = rowptr[n], deg = rowptr[n + 1] - k0;
    int hd = t >> 5;
    float acc[4] = {0, 0, 0, 0};
    for (int c0 = 0; c0 < deg; c0 += 64) {
        int cn = min(64, deg - c0);
        __syncthreads();
        if (t < cn) sidx[t] = colidx[k0 + c0 + t];
        for (int idx = t; idx < cn * NH; idx += 320) sal[idx] = alphaE[(long)(k0 + c0) * NH + idx];
        __syncthreads();
        for (int j = 0; j < cn; j++) {
            int src = sidx[j];
            float a = sal[j * NH + hd];
            f16x4 v = *(const f16x4*)(h + (long)src * HC1 + 4 * t);
            acc[0] += a * (float)v[0];
            acc[1] += a * (float)v[1];
            acc[2] += a * (float)v[2];
            acc[3] += a * (float)v[3];
        }
    }
    f16x4 o;
#pragma unroll
    for (int i = 0; i < 4; i++) {
        float x = acc[i] + bias[4 * t + i];
        o[i] = (_Float16)(x > 0.f ? x : 0.f);
    }
    *(f16x4*)(A2 + (long)n * HC1 + 4 * t) = o;
}

// ---------------- layer-2 aggregation (fp16 gather) + head mean + bias + relu ----------------
__global__ __launch_bounds__(320) void k_agg2(const int* __restrict__ rowptr,
                                              const int* __restrict__ colidx,
                                              const float* __restrict__ alphaE,
                                              const _Float16* __restrict__ h,
                                              const float* __restrict__ bias,
                                              float* __restrict__ out) {
    __shared__ int sidx[64];
    __shared__ float sal[64 * NH];
    __shared__ float facc[HC2];
    int n = blockIdx.x, t = threadIdx.x;
    int k0 = rowptr[n], deg = rowptr[n + 1] - k0;
    int hd = t >> 5;
    float a0 = 0.f, a1 = 0.f;
    for (int c0 = 0; c0 < deg; c0 += 64) {
        int cn = min(64, deg - c0);
        __syncthreads();
        if (t < cn) sidx[t] = colidx[k0 + c0 + t];
        for (int idx = t; idx < cn * NH; idx += 320) sal[idx] = alphaE[(long)(k0 + c0) * NH + idx];
        __syncthreads();
        for (int j = 0; j < cn; j++) {
            int src = sidx[j];
            float a = sal[j * NH + hd];
            f16x2 v = *(const f16x2*)(h + (long)src * HC2 + 2 * t);
            a0 += a * (float)v[0];
            a1 += a * (float)v[1];
        }
    }
    facc[2 * t] = a0;
    facc[2 * t + 1] = a1;
    __syncthreads();
    if (t < C2) {
        float s = 0.f;
#pragma unroll
        for (int hh = 0; hh < NH; hh++) s += facc[hh * C2 + t];
        s = s * 0.1f + bias[t];
        out[(long)n * C2 + t] = s > 0.f ? s : 0.f;
    }
}

// ---------------- host ----------------
extern "C" void kernel_launch(void* const* d_in, const int* in_sizes, int n_in,
                              void* d_out, int out_size, void* d_ws, size_t ws_size,
                              hipStream_t stream) {
    const float* x      = (const float*)d_in[0];
    const int*   ei     = (const int*)d_in[1];
    const float* W1     = (const float*)d_in[2];
    const float* asrc1  = (const float*)d_in[3];
    const float* adst1  = (const float*)d_in[4];
    const float* b1     = (const float*)d_in[5];
    const float* W2     = (const float*)d_in[6];
    const float* asrc2  = (const float*)d_in[7];
    const float* adst2  = (const float*)d_in[8];
    const float* b2     = (const float*)d_in[9];
    float* out = (float*)d_out;
    const int E  = in_sizes[1] / 2;
    const int EN = E + NN;

    char* base = (char*)d_ws;
    size_t o = 0;
    auto alloc = [&](size_t bytes) { size_t r = o; o += (bytes + 255) & ~(size_t)255; return r; };
    _Float16* A1    = (_Float16*)(base + alloc((size_t)MP * K1P * 2));
    _Float16* W1t   = (_Float16*)(base + alloc((size_t)HC1 * K1P * 2));
    _Float16* A2    = (_Float16*)(base + alloc((size_t)MP * HC1 * 2));
    _Float16* W2t   = (_Float16*)(base + alloc((size_t)HC2 * HC1 * 2));
    _Float16* h1pre = (_Float16*)(base + alloc((size_t)MP * HC1 * 2));
    _Float16* h2pre = (_Float16*)(base + alloc((size_t)MP * HC2 * 2));
    float* as1      = (float*)(base + alloc((size_t)NN * NH * 4));
    float* ad1      = (float*)(base + alloc((size_t)NN * NH * 4));
    float* as2      = (float*)(base + alloc((size_t)NN * NH * 4));
    float* ad2      = (float*)(base + alloc((size_t)NN * NH * 4));
    int* counts     = (int*)(base + alloc((size_t)(NN + 1) * 4));
    int* rowptr     = (int*)(base + alloc((size_t)(NN + 1) * 4));
    int* cursor     = (int*)(base + alloc((size_t)(NN + 1) * 4));
    int* colidx     = (int*)(base + alloc((size_t)EN * 4));
    float* alphaE   = (float*)(base + alloc((size_t)EN * NH * 4));
    (void)ws_size; (void)n_in; (void)out_size;

    // ---- layer 1 GEMM: h1pre(fp16) = x @ W1 ----
    k_cast_pad4<<<(MP * (K1P / 4) + 255) / 256, 256, 0, stream>>>(x, A1, NN, FIN / 4, K1P / 4);
    k_transpose_W<<<dim3(K1P / 32, HC1 / 32), 256, 0, stream>>>(W1, W1t, FIN, HC1, K1P);
    k_gemm<<<8 * (MP / 256 / 8) * (HC1 / 128), 256, 0, stream>>>(A1, W1t, h1pre, K1P, HC1, HC1 / 128);

    // ---- CSR (shared by both layers) ----
    k_csr_init<<<(NN + 255) / 256, 256, 0, stream>>>(counts, NN);
    k_csr_count<<<(E + 255) / 256, 256, 0, stream>>>(ei, counts, E);
    k_scan<<<1, 1024, 0, stream>>>(counts, rowptr, cursor, NN);
    k_csr_fill<<<(EN + 255) / 256, 256, 0, stream>>>(ei, cursor, colidx, E, NN);

    // ---- layer 1 attention + aggregate -> A2 fp16 (bias+relu fused) ----
    k_alpha<<<NN, 256, 0, stream>>>(h1pre, asrc1, adst1, as1, ad1, C1);
    k_stats<<<(NN + 3) / 4, 256, 0, stream>>>(rowptr, colidx, as1, ad1, alphaE);
    k_agg1<<<NN, 320, 0, stream>>>(rowptr, colidx, alphaE, h1pre, b1, A2);
    k_zero_f16<<<((MP - NN) * HC1 + 255) / 256, 256, 0, stream>>>(A2 + (long)NN * HC1, (MP - NN) * HC1);

    // ---- layer 2 GEMM: h2pre(fp16) = A2 @ W2 ----
    k_transpose_W<<<dim3(HC1 / 32, HC2 / 32), 256, 0, stream>>>(W2, W2t, HC1, HC2, HC1);
    k_gemm<<<8 * (MP / 256 / 8) * (HC2 / 128), 256, 0, stream>>>(A2, W2t, h2pre, HC1, HC2, HC2 / 128);

    // ---- layer 2 attention + aggregate (mean heads) ----
    k_alpha<<<NN, 256, 0, stream>>>(h2pre, asrc2, adst2, as2, ad2, C2);
    k_stats<<<(NN + 3) / 4, 256, 0, stream>>>(rowptr, colidx, as2, ad2, alphaE);
    k_agg2<<<NN, 320, 0, stream>>>(rowptr, colidx, alphaE, h2pre, b2, out);
}